// Round 5
// baseline (151.478 us; speedup 1.0000x reference)
//
#include <hip/hip_runtime.h>
#include <math.h>

#define NN   192     // N = state = OUT, grid size
#define NIN  64
#define NT   32
#define BLK  192     // 3 waves; thread j owns row j of this block's P_GG slice
#define NW   3

typedef unsigned long long u64;
typedef unsigned int u32;

// Replicated mailboxes: one private region per CONSUMER block.
// Freshness tag lives in the low 8 mantissa bits of each f32 (err ~2^-15 rel).
struct WS {
  u32 hrep [NN][NN];   // [consumer][producer] : bits(h)|tag
  u64 ekrep[NN][NN];   // [consumer][producer] : hi=(bits(e)|tag), lo=(bits(k)|tag)
};

#define REP48(M) M(0)M(1)M(2)M(3)M(4)M(5)M(6)M(7)M(8)M(9)M(10)M(11)M(12)M(13)M(14)M(15)M(16)M(17)M(18)M(19)M(20)M(21)M(22)M(23)M(24)M(25)M(26)M(27)M(28)M(29)M(30)M(31)M(32)M(33)M(34)M(35)M(36)M(37)M(38)M(39)M(40)M(41)M(42)M(43)M(44)M(45)M(46)M(47)

__device__ __forceinline__ u32 pack_h(float v, u32 tag) {
  return (__float_as_uint(v) & ~0xFFu) | tag;
}
__device__ __forceinline__ u64 pack_ek(float e, float k, u32 tag) {
  return ((u64)((__float_as_uint(e) & ~0xFFu) | tag) << 32)
       |  (u64)((__float_as_uint(k) & ~0xFFu) | tag);
}

__device__ __forceinline__ float poll_h(u32* p, u32 tag) {
  u32 v; long g = 0;
  while (true) {
    v = __hip_atomic_load(p, __ATOMIC_RELAXED, __HIP_MEMORY_SCOPE_AGENT);
    if ((v & 0xFFu) == tag) break;
    __builtin_amdgcn_s_sleep(1);
    if (++g > 30000000L) break;    // hang guard
  }
  return __uint_as_float(v & ~0xFFu);
}

__device__ __forceinline__ float2 poll_ek(u64* p, u32 tag) {
  u64 v; long g = 0;
  while (true) {
    v = __hip_atomic_load(p, __ATOMIC_RELAXED, __HIP_MEMORY_SCOPE_AGENT);
    if ((((u32)v & 0xFFu) == tag) & (((u32)(v >> 32) & 0xFFu) == tag)) break;
    __builtin_amdgcn_s_sleep(1);
    if (++g > 30000000L) break;
  }
  return make_float2(__uint_as_float((u32)(v >> 32) & ~0xFFu),
                     __uint_as_float((u32)v & ~0xFFu));
}

// K-way fused block reduction; parity-alternated LDS buffer; ONE __syncthreads.
template <int K>
__device__ __forceinline__ void block_reduceK(float* v, float (*red)[NW], int w, int l) {
  #pragma unroll
  for (int o = 32; o > 0; o >>= 1) {
    #pragma unroll
    for (int q = 0; q < K; ++q) v[q] += __shfl_xor(v[q], o, 64);
  }
  if (l == 0) {
    #pragma unroll
    for (int q = 0; q < K; ++q) red[q][w] = v[q];
  }
  __syncthreads();
  #pragma unroll
  for (int q = 0; q < K; ++q) v[q] = red[q][0] + red[q][1] + red[q][2];
}

extern "C" __global__ void __launch_bounds__(BLK, 1)
force_persistent(const float* __restrict__ x,   const float* __restrict__ y,
                 const float* __restrict__ Win, const float* __restrict__ Wrec,
                 const float* __restrict__ Wout,const float* __restrict__ a0,
                 const float* __restrict__ Pout,const float* __restrict__ Pgg,
                 float* __restrict__ out, WS* __restrict__ ws)
{
  const int b   = blockIdx.x;
  const int tid = threadIdx.x;
  const int w   = tid >> 6;
  const int l   = tid & 63;

  __shared__ __align__(16) float hsS[NN];
  __shared__ __align__(16) float phS[NN];
  __shared__ float red5[2][5][NW];
  __shared__ float red3[2][3][NW];
  __shared__ float xwS[NT];
  __shared__ float yS [NT];

  // ---- init: xw[t] = (x_t @ W_in)[b] (wave0); y column (wave1) ----
  if (w == 0) {
    const float wv = Win[l * NN + b];        // lane l owns input index l (NIN==64)
    float c[NT];
    #pragma unroll
    for (int t2 = 0; t2 < NT; ++t2) c[t2] = x[t2 * NIN + l] * wv;
    #pragma unroll
    for (int o = 32; o > 0; o >>= 1) {
      #pragma unroll
      for (int t2 = 0; t2 < NT; ++t2) c[t2] += __shfl_xor(c[t2], o, 64);
    }
    if (l == 0) {
      #pragma unroll
      for (int t2 = 0; t2 < NT; ++t2) xwS[t2] = c[t2];
    }
  } else if (w == 1 && l < NT) {
    yS[l] = y[l * NN + b];
  }

  // per-thread-owned row/col elements (never touch global again)
  float wrt = Wrec[tid * NN + b];    // W_rec[tid][b]
  float wot = Wout[tid * NN + b];    // W_out[tid][b]
  float po  = Pout[b * NN + tid];    // P_o[b][tid]

  // ---- prologue: h_0; ALL threads publish (one consumer-copy each) ----
  float a_run;
  {
    float v0[1] = { tanhf(a0[tid]) * wrt };
    block_reduceK<1>(v0, red3[1], w, l);   // its barrier also fences xwS/yS
    a_run = 0.9f * a0[b] + 0.1f * (v0[0] + xwS[0]);
    __hip_atomic_store(&ws->hrep[tid][b], pack_h(tanhf(a_run), 1u),
                       __ATOMIC_RELAXED, __HIP_MEMORY_SCOPE_AGENT);
  }

  // ---- P_GG slice b, row `tid`: 48 named float4 regs (loads overlap h0 RT) ----
  #define SDECL(r) float4 s##r;
  REP48(SDECL)
  {
    const float4* srow = (const float4*)(Pgg + (size_t)b * NN * NN + (size_t)tid * NN);
    #define SLOAD(r) s##r = srow[r];
    REP48(SLOAD)
  }

  // deferred-update state from previous step
  float p_prev = 0.f, rden_prev = 0.f, c_prev = 0.f;
  float e_prev_own = 0.f, k_prev_own = 0.f, e_b_prev = 0.f, k_b_prev = 0.f;

  #pragma unroll 1
  for (int t = 0; t < NT; ++t) {
    const u32 tag = (u32)(t + 1);
    const int par = t & 1;

    // ---- poll h_t from OWN private row (coalesced); broadcast via LDS ----
    const float h_own = poll_h(&ws->hrep[b][tid], tag);
    hsS[tid] = h_own;

    // ---- fused 5-way reduction (its barrier also covers hsS) ----
    float v[5];
    v[0] = h_own * wrt;                       // h . W_r_col_b   (stale)
    v[1] = h_own * (p_prev * e_prev_own);     // deferred W_r correction
    v[2] = h_own * wot;                       // h . W_o_col_b   (stale)
    v[3] = h_own * k_prev_own;                // g = h . k_prev
    v[4] = h_own * po;                        // h . P_o_row_b   (stale)
    block_reduceK<5>(v, red5[par], w, l);
    const float ssum_half = v[0] - rden_prev * v[1];         // h . W_r^{t-1}
    const float g   = v[3];
    const float z   = v[2] - c_prev * e_b_prev * g;          // h . W_o^{t-1}
    const float kb  = v[4] - c_prev * k_b_prev * g;          // P_o^{t-1} h
    const float eb  = z - yS[t];
    // all threads hold eb/kb -> push one copy to consumer `tid`'s slot b
    __hip_atomic_store(&ws->ekrep[tid][b], pack_ek(eb, kb, tag),
                       __ATOMIC_RELAXED, __HIP_MEMORY_SCOPE_AGENT);
    if (tid == 0) out[t * NN + b] = z;
    if (t == NT - 1) break;                   // final outputs published; done

    // ---- lazy row updates (off critical path) ----
    wrt -= rden_prev * p_prev * e_prev_own;
    wot -= c_prev * k_prev_own * e_b_prev;
    po  -= c_prev * k_b_prev  * k_prev_own;

    // ---- Phase C: p = S_row . h_t (4 chains); hides ek RT ----
    const float4* h4 = (const float4*)hsS;
    float4 acc = make_float4(0.f, 0.f, 0.f, 0.f);
    #define PHC(r) { const float4 hv = h4[r]; \
                     acc.x += s##r.x*hv.x; acc.y += s##r.y*hv.y; \
                     acc.z += s##r.z*hv.z; acc.w += s##r.w*hv.w; }
    REP48(PHC)
    const float p = (acc.x + acc.y) + (acc.z + acc.w);
    phS[tid] = p;                              // fenced by reduce3's barrier

    // ---- poll e_t, k_t from OWN private row ----
    const float2 ek = poll_ek(&ws->ekrep[b][tid], tag);
    const float e_own = ek.x, k_own = ek.y;

    // ---- fused 3-way reduction: hk, corr2, hPh ----
    float u[3];
    u[0] = k_own * h_own;
    u[1] = h_own * p * e_own;
    u[2] = p * h_own;
    block_reduceK<3>(u, red3[par], w, l);
    const float rden = 1.f / (1.f + u[2]);
    const float c1   = 1.f / (1.f + u[0]);

    // ---- a-update; ALL threads publish h_{t+1} (one copy each) ----
    a_run = 0.9f * a_run + 0.1f * (ssum_half - rden * u[1] + xwS[t + 1]);
    const float hnext = tanhf(a_run);
    __hip_atomic_store(&ws->hrep[tid][b], pack_h(hnext, tag + 1u),
                       __ATOMIC_RELAXED, __HIP_MEMORY_SCOPE_AGENT);

    // ---- Phase D: S -= (rden*p) * Ph  (off critical path; hides h RT) ----
    const float rv = rden * p;
    const float4* ph4 = (const float4*)phS;
    #define PHD(r) { const float4 pv = ph4[r]; \
                     s##r.x -= rv*pv.x; s##r.y -= rv*pv.y; \
                     s##r.z -= rv*pv.z; s##r.w -= rv*pv.w; }
    REP48(PHD)

    // ---- roll deferred state ----
    p_prev = p; rden_prev = rden; c_prev = c1;
    e_prev_own = e_own; k_prev_own = k_own; e_b_prev = eb; k_b_prev = kb;
  }
}

extern "C" void kernel_launch(void* const* d_in, const int* in_sizes, int n_in,
                              void* d_out, int out_size, void* d_ws, size_t ws_size,
                              hipStream_t stream) {
  const float* x    = (const float*)d_in[0];
  const float* y    = (const float*)d_in[1];
  const float* Win  = (const float*)d_in[2];
  const float* Wrec = (const float*)d_in[3];
  const float* Wout = (const float*)d_in[4];
  const float* a0   = (const float*)d_in[5];
  const float* Pout = (const float*)d_in[6];
  const float* Pgg  = (const float*)d_in[7];
  float* out = (float*)d_out;
  WS* ws = (WS*)d_ws;
  (void)in_sizes; (void)n_in; (void)out_size; (void)ws_size;

  // reset all mailbox tags each call (graph replays must not see stale tags)
  hipMemsetAsync(ws, 0, sizeof(WS), stream);
  force_persistent<<<NN, BLK, 0, stream>>>(x, y, Win, Wrec, Wout, a0, Pout, Pgg, out, ws);
}

// Round 6
// 144.407 us; speedup vs baseline: 1.0490x; 1.0490x over previous
//
#include <hip/hip_runtime.h>
#include <math.h>

#define NN   192     // N = state = OUT, grid size
#define NIN  64
#define NT   32
#define BLK  192     // 3 waves; thread j owns row j of this block's P_GG slice
#define NW   3
#define NREP 8       // XCD-hashed mailbox replicas

typedef unsigned long long u64;
typedef unsigned int u32;

// Pull-model tagged slots (round-4 design), replicated 8x to cut per-line
// polling contention. Producers write all replicas; consumer b polls b&7.
struct HSlot { u64 v; u64 pad; };    // 16B padded: 4 producers per 64B line
struct WS {
  HSlot hrep [NREP][NN];             // (tag<<32)|bits(h_b)
  u64   ekrep[NREP][NN][2];          // [0]=(tag,e_b) [1]=(tag,k_b) : 16B/producer
};

#define REP48(M) M(0)M(1)M(2)M(3)M(4)M(5)M(6)M(7)M(8)M(9)M(10)M(11)M(12)M(13)M(14)M(15)M(16)M(17)M(18)M(19)M(20)M(21)M(22)M(23)M(24)M(25)M(26)M(27)M(28)M(29)M(30)M(31)M(32)M(33)M(34)M(35)M(36)M(37)M(38)M(39)M(40)M(41)M(42)M(43)M(44)M(45)M(46)M(47)

__device__ __forceinline__ u64 packf(float v, u32 tag) {
  return ((u64)tag << 32) | (u64)__float_as_uint(v);
}

__device__ __forceinline__ float poll_slot(u64* p, u32 tag) {
  u64 v; long g = 0;
  while (true) {
    v = __hip_atomic_load(p, __ATOMIC_RELAXED, __HIP_MEMORY_SCOPE_AGENT);
    if ((u32)(v >> 32) == tag) break;
    __builtin_amdgcn_s_sleep(2);
    if (++g > 30000000L) break;    // hang guard
  }
  return __uint_as_float((u32)v);
}

__device__ __forceinline__ float2 poll_ek(u64* p, u32 tag) {
  u64 va, vb; long g = 0;
  while (true) {
    va = __hip_atomic_load(p,     __ATOMIC_RELAXED, __HIP_MEMORY_SCOPE_AGENT);
    vb = __hip_atomic_load(p + 1, __ATOMIC_RELAXED, __HIP_MEMORY_SCOPE_AGENT);
    if (((u32)(va >> 32) == tag) & ((u32)(vb >> 32) == tag)) break;
    __builtin_amdgcn_s_sleep(2);
    if (++g > 30000000L) break;
  }
  return make_float2(__uint_as_float((u32)va), __uint_as_float((u32)vb));
}

// K-way fused block reduction; parity-alternated LDS buffer; ONE __syncthreads.
template <int K>
__device__ __forceinline__ void block_reduceK(float* v, float (*red)[NW], int w, int l) {
  #pragma unroll
  for (int o = 32; o > 0; o >>= 1) {
    #pragma unroll
    for (int q = 0; q < K; ++q) v[q] += __shfl_xor(v[q], o, 64);
  }
  if (l == 0) {
    #pragma unroll
    for (int q = 0; q < K; ++q) red[q][w] = v[q];
  }
  __syncthreads();
  #pragma unroll
  for (int q = 0; q < K; ++q) v[q] = red[q][0] + red[q][1] + red[q][2];
}

extern "C" __global__ void __launch_bounds__(BLK, 1)
force_persistent(const float* __restrict__ x,   const float* __restrict__ y,
                 const float* __restrict__ Win, const float* __restrict__ Wrec,
                 const float* __restrict__ Wout,const float* __restrict__ a0,
                 const float* __restrict__ Pout,const float* __restrict__ Pgg,
                 float* __restrict__ out, WS* __restrict__ ws)
{
  const int b   = blockIdx.x;
  const int tid = threadIdx.x;
  const int w   = tid >> 6;
  const int l   = tid & 63;
  const int rep = b & (NREP - 1);    // replica this block polls

  __shared__ __align__(16) float hsS[NN];
  __shared__ __align__(16) float phS[NN];
  __shared__ float red5[2][5][NW];
  __shared__ float red3[2][3][NW];
  __shared__ float xwS[NT];
  __shared__ float yS [NT];

  // ---- init: xw[t] = (x_t @ W_in)[b] (wave0); y column (wave1) ----
  if (w == 0) {
    const float wv = Win[l * NN + b];        // lane l owns input index l (NIN==64)
    float c[NT];
    #pragma unroll
    for (int t2 = 0; t2 < NT; ++t2) c[t2] = x[t2 * NIN + l] * wv;
    #pragma unroll
    for (int o = 32; o > 0; o >>= 1) {
      #pragma unroll
      for (int t2 = 0; t2 < NT; ++t2) c[t2] += __shfl_xor(c[t2], o, 64);
    }
    if (l == 0) {
      #pragma unroll
      for (int t2 = 0; t2 < NT; ++t2) xwS[t2] = c[t2];
    }
  } else if (w == 1 && l < NT) {
    yS[l] = y[l * NN + b];
  }

  // per-thread-owned row/col elements (never touch global again)
  float wrt = Wrec[tid * NN + b];    // W_rec[tid][b]
  float wot = Wout[tid * NN + b];    // W_out[tid][b]
  float po  = Pout[b * NN + tid];    // P_o[b][tid]

  // ---- prologue: h_0; lanes 0..7 publish one replica each ----
  float a_run;
  {
    float v0[1] = { tanhf(a0[tid]) * wrt };
    block_reduceK<1>(v0, red3[1], w, l);   // its barrier also fences xwS/yS
    a_run = 0.9f * a0[b] + 0.1f * (v0[0] + xwS[0]);
    const float h0 = tanhf(a_run);
    if (tid < NREP)
      __hip_atomic_store(&ws->hrep[tid][b].v, packf(h0, 1u),
                         __ATOMIC_RELAXED, __HIP_MEMORY_SCOPE_AGENT);
  }

  // ---- P_GG slice b, row `tid`: 48 named float4 regs (loads overlap h0 RT) ----
  #define SDECL(r) float4 s##r;
  REP48(SDECL)
  {
    const float4* srow = (const float4*)(Pgg + (size_t)b * NN * NN + (size_t)tid * NN);
    #define SLOAD(r) s##r = srow[r];
    REP48(SLOAD)
  }

  // deferred-update state from previous step
  float p_prev = 0.f, rden_prev = 0.f, c_prev = 0.f;
  float e_prev_own = 0.f, k_prev_own = 0.f, e_b_prev = 0.f, k_b_prev = 0.f;

  #pragma unroll 1
  for (int t = 0; t < NT; ++t) {
    const u32 tag = (u32)(t + 1);
    const int par = t & 1;

    // ---- poll h_t from own replica; broadcast via LDS ----
    const float h_own = poll_slot(&ws->hrep[rep][tid].v, tag);
    hsS[tid] = h_own;

    // ---- fused 5-way reduction (its barrier also covers hsS) ----
    float v[5];
    v[0] = h_own * wrt;                       // h . W_r_col_b   (stale)
    v[1] = h_own * (p_prev * e_prev_own);     // deferred W_r correction
    v[2] = h_own * wot;                       // h . W_o_col_b   (stale)
    v[3] = h_own * k_prev_own;                // g = h . k_prev
    v[4] = h_own * po;                        // h . P_o_row_b   (stale)
    block_reduceK<5>(v, red5[par], w, l);
    const float ssum_half = v[0] - rden_prev * v[1];         // h . W_r^{t-1}
    const float g   = v[3];
    const float z   = v[2] - c_prev * e_b_prev * g;          // h . W_o^{t-1}
    const float kb  = v[4] - c_prev * k_b_prev * g;          // P_o^{t-1} h
    const float eb  = z - yS[t];
    // lanes 0..7 publish (e,k) to one replica each (fire-and-forget)
    if (tid < NREP) {
      __hip_atomic_store(&ws->ekrep[tid][b][0], packf(eb, tag),
                         __ATOMIC_RELAXED, __HIP_MEMORY_SCOPE_AGENT);
      __hip_atomic_store(&ws->ekrep[tid][b][1], packf(kb, tag),
                         __ATOMIC_RELAXED, __HIP_MEMORY_SCOPE_AGENT);
    }
    if (tid == 0) out[t * NN + b] = z;
    if (t == NT - 1) break;                   // final outputs published; done

    // ---- lazy row updates (off critical path) ----
    wrt -= rden_prev * p_prev * e_prev_own;
    wot -= c_prev * k_prev_own * e_b_prev;
    po  -= c_prev * k_b_prev  * k_prev_own;

    // ---- Phase C: p = S_row . h_t (4 chains); hides ek RT ----
    const float4* h4 = (const float4*)hsS;
    float4 acc = make_float4(0.f, 0.f, 0.f, 0.f);
    #define PHC(r) { const float4 hv = h4[r]; \
                     acc.x += s##r.x*hv.x; acc.y += s##r.y*hv.y; \
                     acc.z += s##r.z*hv.z; acc.w += s##r.w*hv.w; }
    REP48(PHC)
    const float p = (acc.x + acc.y) + (acc.z + acc.w);
    phS[tid] = p;                              // fenced by reduce3's barrier

    // ---- poll e_t, k_t from own replica ----
    const float2 ek = poll_ek(&ws->ekrep[rep][tid][0], tag);
    const float e_own = ek.x, k_own = ek.y;

    // ---- fused 3-way reduction: hk, corr2, hPh ----
    float u[3];
    u[0] = k_own * h_own;
    u[1] = h_own * p * e_own;
    u[2] = p * h_own;
    block_reduceK<3>(u, red3[par], w, l);
    const float rden = 1.f / (1.f + u[2]);
    const float c1   = 1.f / (1.f + u[0]);

    // ---- a-update; lanes 0..7 publish h_{t+1} ----
    a_run = 0.9f * a_run + 0.1f * (ssum_half - rden * u[1] + xwS[t + 1]);
    const float hnext = tanhf(a_run);
    if (tid < NREP)
      __hip_atomic_store(&ws->hrep[tid][b].v, packf(hnext, tag + 1u),
                         __ATOMIC_RELAXED, __HIP_MEMORY_SCOPE_AGENT);

    // ---- Phase D: S -= (rden*p) * Ph  (off critical path; hides h RT) ----
    const float rv = rden * p;
    const float4* ph4 = (const float4*)phS;
    #define PHD(r) { const float4 pv = ph4[r]; \
                     s##r.x -= rv*pv.x; s##r.y -= rv*pv.y; \
                     s##r.z -= rv*pv.z; s##r.w -= rv*pv.w; }
    REP48(PHD)

    // ---- roll deferred state ----
    p_prev = p; rden_prev = rden; c_prev = c1;
    e_prev_own = e_own; k_prev_own = k_own; e_b_prev = eb; k_b_prev = kb;
  }
}

extern "C" void kernel_launch(void* const* d_in, const int* in_sizes, int n_in,
                              void* d_out, int out_size, void* d_ws, size_t ws_size,
                              hipStream_t stream) {
  const float* x    = (const float*)d_in[0];
  const float* y    = (const float*)d_in[1];
  const float* Win  = (const float*)d_in[2];
  const float* Wrec = (const float*)d_in[3];
  const float* Wout = (const float*)d_in[4];
  const float* a0   = (const float*)d_in[5];
  const float* Pout = (const float*)d_in[6];
  const float* Pgg  = (const float*)d_in[7];
  float* out = (float*)d_out;
  WS* ws = (WS*)d_ws;
  (void)in_sizes; (void)n_in; (void)out_size; (void)ws_size;

  // reset all slot tags each call (graph replays must not see stale tags)
  hipMemsetAsync(ws, 0, sizeof(WS), stream);
  force_persistent<<<NN, BLK, 0, stream>>>(x, y, Win, Wrec, Wout, a0, Pout, Pgg, out, ws);
}